// Round 8
// baseline (50.931 us; speedup 1.0000x reference)
//
#include <hip/hip_runtime.h>

#define RADIUS2 0.01f
#define NS 32
#define B_ 4
#define M_ 2048
#define N_ 8192
#define C_ 64
#define OUTW 67               // 3 + C
#define PERQ (NS * OUTW)      // 2144 floats per query
#define GD 10                 // cells per axis (cell width = radius)
#define NC (GD * GD * GD)     // 1000
#define CAP 128               // max candidates kept (Poisson(34); P(>128)~1e-30)

typedef float f32x4  __attribute__((ext_vector_type(4)));
typedef float f32x4u __attribute__((ext_vector_type(4), aligned(4)));  // 4B-aligned vec

__device__ __forceinline__ int clamp9(int v) { return v < 0 ? 0 : (v > 9 ? 9 : v); }

// ---- grid build: one block per batch; emits points sorted by cell ----
__global__ __launch_bounds__(1024) void build_grid(
    const float* __restrict__ pointset,  // [B,N,3]
    int* __restrict__ cellstart,         // [B][NC+1]
    float4* __restrict__ sorted4)        // [B][N]: x,y,z,orig-idx bits
{
    const int b   = blockIdx.x;
    const int tid = threadIdx.x;
    const float* __restrict__ ps = pointset + (size_t)b * N_ * 3;
    int* __restrict__ cs = cellstart + b * (NC + 1);
    float4* __restrict__ sp = sorted4 + (size_t)b * N_;

    __shared__ int scnt[NC], sstart[NC], sfill[NC];

    for (int c = tid; c < NC; c += 1024) { scnt[c] = 0; sfill[c] = 0; }
    __syncthreads();

    for (int i = tid; i < N_; i += 1024) {
        const int cx = clamp9((int)(ps[i*3+0] * 10.f));
        const int cy = clamp9((int)(ps[i*3+1] * 10.f));
        const int cz = clamp9((int)(ps[i*3+2] * 10.f));
        atomicAdd(&scnt[(cz * GD + cy) * GD + cx], 1);
    }
    __syncthreads();

    for (int off = 1; off < NC; off <<= 1) {       // inclusive scan
        int v = 0;
        if (tid < NC && tid >= off) v = scnt[tid - off];
        __syncthreads();
        if (tid < NC) scnt[tid] += v;
        __syncthreads();
    }
    if (tid < NC) sstart[tid] = tid ? scnt[tid - 1] : 0;
    __syncthreads();
    if (tid < NC) cs[tid] = sstart[tid];
    if (tid == 0) cs[NC] = N_;

    for (int i = tid; i < N_; i += 1024) {
        const float x = ps[i*3+0], y = ps[i*3+1], z = ps[i*3+2];
        const int c = (clamp9((int)(z * 10.f)) * GD + clamp9((int)(y * 10.f))) * GD
                      + clamp9((int)(x * 10.f));
        const int pos = sstart[c] + atomicAdd(&sfill[c], 1);
        sp[pos] = make_float4(x, y, z, __int_as_float(i));
    }
}

// ---- query + group: one wave per query; no barriers ----
__global__ __launch_bounds__(256) void query_group(
    const float* __restrict__ new_xyz,   // [B,M,3]
    const float* __restrict__ pointset,  // [B,N,3] (only for the cnt==0 corner)
    const float* __restrict__ feature,   // [B,N,C]
    const int* __restrict__ cellstart,   // [B][NC+1]
    const float4* __restrict__ sorted4,  // [B][N]
    float* __restrict__ out)             // [B,M,NS,67]
{
    const int w    = threadIdx.x >> 6;
    const int lane = threadIdx.x & 63;
    // XCD-bijective swizzle (2048 blocks % 8 == 0): confine each XCD to one batch
    const int bid  = blockIdx.x;
    const int swz  = (bid & 7) * 256 + (bid >> 3);
    const int q    = swz * 4 + w;
    const int b    = q >> 11;            // q / M

    __shared__ f32x4 cand4[4][CAP];      // per-wave: x,y,z,idx-bits
    __shared__ f32x4 sfin4[4][NS];       // per-wave: final 32 records

    const float* __restrict__ ps  = pointset + (size_t)b * N_ * 3;
    const int* __restrict__ cs    = cellstart + b * (NC + 1);
    const float4* __restrict__ sp4 = sorted4 + (size_t)b * N_;

    const float qx = new_xyz[q*3+0];
    const float qy = new_xyz[q*3+1];
    const float qz = new_xyz[q*3+2];

    const int cx = clamp9((int)(qx * 10.f));
    const int cy = clamp9((int)(qy * 10.f));
    const int cz = clamp9((int)(qz * 10.f));
    const int x0 = cx > 0 ? cx - 1 : 0, x1 = cx < 9 ? cx + 1 : 9;

    // prefetch all 9 row-range bounds upfront (18 independent loads in flight)
    int rs[9], re[9];
#pragma unroll
    for (int dz = 0; dz < 3; ++dz) {
#pragma unroll
        for (int dy = 0; dy < 3; ++dy) {
            const int zz = cz + dz - 1, yy = cy + dy - 1;
            const int r  = dz * 3 + dy;
            if (zz >= 0 && zz < GD && yy >= 0 && yy < GD) {
                const int base = (zz * GD + yy) * GD;
                rs[r] = cs[base + x0];
                re[r] = cs[base + x1 + 1];
            } else { rs[r] = 0; re[r] = 0; }
        }
    }

    // collect in-ball candidates (coalesced float4 over contiguous ranges)
    int ncand = 0;
#pragma unroll
    for (int r = 0; r < 9; ++r) {
        const int s = rs[r], e = re[r];
        for (int j0 = s; j0 < e; j0 += 64) {
            const int j = j0 + lane;
            const float4 v = sp4[j < e ? j : e - 1];
            const float dx = qx - v.x;
            const float dy = qy - v.y;
            const float dz = qz - v.z;
            // exact non-fma sum of squares (matches reference ties)
            const float d2 = __fadd_rn(__fadd_rn(__fmul_rn(dx,dx), __fmul_rn(dy,dy)),
                                       __fmul_rn(dz,dz));
            const bool in = (j < e) && (d2 < RADIUS2);
            const unsigned long long mk = __ballot(in);
            if (in) {
                const unsigned pre = __builtin_amdgcn_mbcnt_hi(
                    (unsigned)(mk >> 32),
                    __builtin_amdgcn_mbcnt_lo((unsigned)mk, 0u));
                const int slot = ncand + (int)pre;
                if (slot < CAP) cand4[w][slot] = (f32x4){v.x, v.y, v.z, v.w};
            }
            ncand += (int)__popcll(mk);
        }
    }
    if (ncand > CAP) ncand = CAP;

    // rank candidates by original index -> first-32-in-index-order semantics
    int i0 = 0x7fffffff, i1 = 0x7fffffff;
    if (lane      < ncand) i0 = __float_as_int(cand4[w][lane].w);
    if (lane + 64 < ncand) i1 = __float_as_int(cand4[w][lane + 64].w);
    int r0 = 0, r1 = 0;
    const float* candw = (const float*)&cand4[w][0];
    for (int j = 0; j < ncand; ++j) {
        const int cj = __float_as_int(candw[j * 4 + 3]);   // broadcast read
        r0 += (cj < i0);
        r1 += (cj < i1);
    }
    const int cnt = ncand < NS ? ncand : NS;
    if (i0 != 0x7fffffff && r0 < NS) sfin4[w][r0] = cand4[w][lane];
    if (i1 != 0x7fffffff && r1 < NS) sfin4[w][r1] = cand4[w][lane + 64];
    if (ncand == 0 && lane == 0)     // CUDA semantics: no neighbor -> point 0
        sfin4[w][0] = (f32x4){ps[0], ps[1], ps[2], __int_as_float(0)};
    // fill slots >= cnt with the first (lowest-index) record
    if (lane < NS && lane >= cnt) sfin4[w][lane] = sfin4[w][0];

    // ---- phase 2: feature gather as (sample, 16B-chunk) items ----
    const float* __restrict__ fb = feature + (size_t)b * N_ * C_;
    float* __restrict__ outq = out + (size_t)q * PERQ;

#pragma unroll
    for (int h = 0; h < 2; ++h) {        // 2 groups of 4 iters (VGPR-friendly)
        int sv[4], kv[4], iv[4];
        f32x4u data[4];
#pragma unroll
        for (int t = 0; t < 4; ++t) {
            const int item = (h * 4 + t) * 64 + lane;    // 0..511
            sv[t] = item >> 4;                           // sample 0..31
            kv[t] = item & 15;                           // 16B chunk 0..15
            iv[t] = __float_as_int(sfin4[w][sv[t]].w);   // LDS broadcast
        }
#pragma unroll
        for (int t = 0; t < 4; ++t)      // 1 dwordx4 = 4 rows x 256B coalesced
            data[t] = *(const f32x4u*)(fb + (size_t)iv[t] * C_ + kv[t] * 4);
#pragma unroll
        for (int t = 0; t < 4; ++t)
            __builtin_nontemporal_store(
                data[t], (f32x4u*)(outq + sv[t] * OUTW + 3 + kv[t] * 4));
    }
    // xyz prefix: from the LDS record — no global gather
    if (lane < NS) {
        const f32x4 v = sfin4[w][lane];
        float* o = outq + lane * OUTW;
        __builtin_nontemporal_store(v.x - qx, o + 0);    // local_xyz = p - q
        __builtin_nontemporal_store(v.y - qy, o + 1);
        __builtin_nontemporal_store(v.z - qz, o + 2);
    }
}

// ---- fallback (proven R3 kernel) if ws too small ----
#define NWF 8
#define TILEF 1024
#define NTILEF (N_ / TILEF)

__global__ __launch_bounds__(NWF * 64) void ballquery_fallback(
    const float* __restrict__ new_xyz, const float* __restrict__ pointset,
    const float* __restrict__ feature, float* __restrict__ out)
{
    const int tid  = threadIdx.x;
    const int w    = tid >> 6;
    const int lane = tid & 63;
    const int q    = blockIdx.x * NWF + w;
    const int b    = q >> 11;

    __shared__ float4 spts[TILEF];
    __shared__ int    sidx[NWF][NS];
    __shared__ int    s_done;

    const float qx = new_xyz[q*3+0], qy = new_xyz[q*3+1], qz = new_xyz[q*3+2];
    const float* __restrict__ ps = pointset + (size_t)b * N_ * 3;

    if (tid == 0) s_done = 0;
    int cnt = 0; bool counted = false;

    for (int t = 0; t < NTILEF; ++t) {
        __syncthreads();
        if (s_done == NWF) break;
        {
            const float* __restrict__ tp = ps + t * TILEF * 3;
            float* __restrict__ sp = (float*)spts;
            for (int d = tid; d < TILEF * 3; d += NWF * 64) {
                const int p = d / 3;
                sp[p * 4 + (d - p * 3)] = tp[d];
            }
        }
        __syncthreads();
        if (cnt < NS) {
#pragma unroll 4
            for (int it = 0; it < TILEF / 64; ++it) {
                const float4 p = spts[it * 64 + lane];
                const float dx = qx - p.x, dy = qy - p.y, dz = qz - p.z;
                const float d2 = __fadd_rn(__fadd_rn(__fmul_rn(dx,dx), __fmul_rn(dy,dy)),
                                           __fmul_rn(dz,dz));
                const bool in = d2 < RADIUS2;
                const unsigned long long mk = __ballot(in);
                const unsigned pre = __builtin_amdgcn_mbcnt_hi(
                    (unsigned)(mk >> 32), __builtin_amdgcn_mbcnt_lo((unsigned)mk, 0u));
                if (in) {
                    const int slot = cnt + (int)pre;
                    if (slot < NS) sidx[w][slot] = t * TILEF + it * 64 + lane;
                }
                cnt += (int)__popcll(mk);
            }
        }
        if (!counted && cnt >= NS) { counted = true; if (lane == 0) atomicAdd(&s_done, 1); }
    }
    if (cnt > NS) cnt = NS;
    const int first = (cnt > 0) ? sidx[w][0] : 0;
    if (lane < NS && lane >= cnt) sidx[w][lane] = first;

    const float* __restrict__ fb = feature + (size_t)b * N_ * C_;
    float* __restrict__ outq = out + (size_t)q * PERQ;
    int s = 0, c = lane;
    for (int o = lane; o < PERQ; o += 64) {
        const int i = sidx[w][s];
        float v;
        if (c < 3) v = ps[i*3+c] - new_xyz[q*3+c];
        else       v = fb[(size_t)i * C_ + (c - 3)];
        outq[o] = v;
        c += 64;
        if (c >= OUTW) { c -= OUTW; s += 1; }
    }
}

extern "C" void kernel_launch(void* const* d_in, const int* in_sizes, int n_in,
                              void* d_out, int out_size, void* d_ws, size_t ws_size,
                              hipStream_t stream) {
    const float* new_xyz  = (const float*)d_in[0];
    const float* pointset = (const float*)d_in[1];
    const float* feature  = (const float*)d_in[2];
    float* out = (float*)d_out;

    const size_t cs_bytes = (size_t)B_ * (NC + 1) * sizeof(int);   // 16016 (16B aligned)
    const size_t needed   = cs_bytes + (size_t)B_ * N_ * sizeof(float4);
    if (ws_size >= needed) {
        int*    cellstart = (int*)d_ws;
        float4* sorted4   = (float4*)((char*)d_ws + cs_bytes);
        build_grid<<<B_, 1024, 0, stream>>>(pointset, cellstart, sorted4);
        query_group<<<(B_ * M_) / 4, 256, 0, stream>>>(
            new_xyz, pointset, feature, cellstart, sorted4, out);
    } else {
        ballquery_fallback<<<(B_ * M_) / NWF, NWF * 64, 0, stream>>>(
            new_xyz, pointset, feature, out);
    }
}

// Round 9
// 34.756 us; speedup vs baseline: 1.4654x; 1.4654x over previous
//
#include <hip/hip_runtime.h>

#define RADIUS2 0.01f
#define NS 32
#define B_ 4
#define M_ 2048
#define N_ 8192
#define C_ 64
#define OUTW 67               // 3 + C
#define PERQ (NS * OUTW)      // 2144 floats per query (8576 B = 134 full lines)
#define PERQ4 (PERQ / 4)      // 536 aligned f32x4 per query
#define GD 10                 // cells per axis (cell width = radius)
#define NC (GD * GD * GD)     // 1000
#define CAP 128               // max candidates (Poisson(34); P(>128) ~ 1e-33)
#define ROWW 68               // LDS row stride: pad,xyz,64 feats

typedef float f32x4 __attribute__((ext_vector_type(4)));

__device__ __forceinline__ int clamp9(int v) { return v < 0 ? 0 : (v > 9 ? 9 : v); }

// ---- grid build: one block per batch; emits points sorted by cell ----
__global__ __launch_bounds__(1024) void build_grid(
    const float* __restrict__ pointset,  // [B,N,3]
    int* __restrict__ cellstart,         // [B][NC+1]
    float4* __restrict__ sorted4)        // [B][N]: x,y,z,orig-idx bits
{
    const int b   = blockIdx.x;
    const int tid = threadIdx.x;
    const float* __restrict__ ps = pointset + (size_t)b * N_ * 3;
    int* __restrict__ cs = cellstart + b * (NC + 1);
    float4* __restrict__ sp = sorted4 + (size_t)b * N_;

    __shared__ int scnt[NC], sstart[NC], sfill[NC];

    for (int c = tid; c < NC; c += 1024) { scnt[c] = 0; sfill[c] = 0; }
    __syncthreads();

    for (int i = tid; i < N_; i += 1024) {
        const int cx = clamp9((int)(ps[i*3+0] * 10.f));
        const int cy = clamp9((int)(ps[i*3+1] * 10.f));
        const int cz = clamp9((int)(ps[i*3+2] * 10.f));
        atomicAdd(&scnt[(cz * GD + cy) * GD + cx], 1);
    }
    __syncthreads();

    for (int off = 1; off < NC; off <<= 1) {       // inclusive scan
        int v = 0;
        if (tid < NC && tid >= off) v = scnt[tid - off];
        __syncthreads();
        if (tid < NC) scnt[tid] += v;
        __syncthreads();
    }
    if (tid < NC) sstart[tid] = tid ? scnt[tid - 1] : 0;
    __syncthreads();
    if (tid < NC) cs[tid] = sstart[tid];
    if (tid == 0) cs[NC] = N_;

    for (int i = tid; i < N_; i += 1024) {
        const float x = ps[i*3+0], y = ps[i*3+1], z = ps[i*3+2];
        const int c = (clamp9((int)(z * 10.f)) * GD + clamp9((int)(y * 10.f))) * GD
                      + clamp9((int)(x * 10.f));
        const int pos = sstart[c] + atomicAdd(&sfill[c], 1);
        sp[pos] = make_float4(x, y, z, __int_as_float(i));
    }
}

// ---- query + group: one wave per query; no barriers ----
__global__ __launch_bounds__(256, 4) void query_group(
    const float* __restrict__ new_xyz,   // [B,M,3]
    const float* __restrict__ pointset,  // [B,N,3] (cnt==0 corner only)
    const float* __restrict__ feature,   // [B,N,C]
    const int* __restrict__ cellstart,   // [B][NC+1]
    const float4* __restrict__ sorted4,  // [B][N]
    float* __restrict__ out)             // [B,M,NS,67]
{
    const int w    = threadIdx.x >> 6;
    const int lane = threadIdx.x & 63;
    // XCD-bijective swizzle (2048 blocks % 8 == 0): each XCD-pair owns one batch
    const int bid  = blockIdx.x;
    const int swz  = (bid & 7) * 256 + (bid >> 3);
    const int q    = swz * 4 + w;
    const int b    = q >> 11;            // q / M

    // per-wave scratch: candidate buffer (phase 1) unioned with row buffer (phase 2)
    __shared__ __align__(16) float srow[4][NS * ROWW];   // 8704 B per wave
    __shared__ f32x4 sfin4[4][NS];                       // final records x,y,z,idx

    float* __restrict__ srw   = srow[w];
    f32x4* __restrict__ cand4 = (f32x4*)srow[w];         // first 2 KB, dead after rank

    const float* __restrict__ ps   = pointset + (size_t)b * N_ * 3;
    const int* __restrict__ cs     = cellstart + b * (NC + 1);
    const float4* __restrict__ sp4 = sorted4 + (size_t)b * N_;

    const float qx = new_xyz[q*3+0];
    const float qy = new_xyz[q*3+1];
    const float qz = new_xyz[q*3+2];

    const int cx = clamp9((int)(qx * 10.f));
    const int cy = clamp9((int)(qy * 10.f));
    const int cz = clamp9((int)(qz * 10.f));
    const int x0 = cx > 0 ? cx - 1 : 0, x1 = cx < 9 ? cx + 1 : 9;

    // prefetch all 9 row-range bounds upfront (independent scalar loads)
    int rs[9], re[9];
#pragma unroll
    for (int dz = 0; dz < 3; ++dz) {
#pragma unroll
        for (int dy = 0; dy < 3; ++dy) {
            const int zz = cz + dz - 1, yy = cy + dy - 1;
            const int r  = dz * 3 + dy;
            if (zz >= 0 && zz < GD && yy >= 0 && yy < GD) {
                const int base = (zz * GD + yy) * GD;
                rs[r] = cs[base + x0];
                re[r] = cs[base + x1 + 1];
            } else { rs[r] = 0; re[r] = 0; }
        }
    }

    // ---- phase 1: collect in-ball candidates (coalesced float4 ranges) ----
    int ncand = 0;
#pragma unroll
    for (int r = 0; r < 9; ++r) {
        const int s = rs[r], e = re[r];
        for (int j0 = s; j0 < e; j0 += 64) {
            const int j = j0 + lane;
            const float4 v = sp4[j < e ? j : e - 1];
            const float dx = qx - v.x;
            const float dy = qy - v.y;
            const float dz = qz - v.z;
            // exact non-fma sum of squares (matches reference ties)
            const float d2 = __fadd_rn(__fadd_rn(__fmul_rn(dx,dx), __fmul_rn(dy,dy)),
                                       __fmul_rn(dz,dz));
            const bool in = (j < e) && (d2 < RADIUS2);
            const unsigned long long mk = __ballot(in);
            if (in) {
                const unsigned pre = __builtin_amdgcn_mbcnt_hi(
                    (unsigned)(mk >> 32),
                    __builtin_amdgcn_mbcnt_lo((unsigned)mk, 0u));
                const int slot = ncand + (int)pre;
                if (slot < CAP) cand4[slot] = (f32x4){v.x, v.y, v.z, v.w};
            }
            ncand += (int)__popcll(mk);
        }
    }
    if (ncand > CAP) ncand = CAP;

    // ---- rank by original index -> first-32-in-index-order ----
    int i0 = 0x7fffffff, i1 = 0x7fffffff;
    f32x4 rec0, rec1;
    if (lane      < ncand) { rec0 = cand4[lane];      i0 = __float_as_int(rec0.w); }
    if (lane + 64 < ncand) { rec1 = cand4[lane + 64]; i1 = __float_as_int(rec1.w); }
    int r0 = 0, r1 = 0;
    for (int j = 0; j < ncand; ++j) {
        const int cj = __float_as_int(srw[j * 4 + 3]);  // broadcast read
        r0 += (cj < i0);
        r1 += (cj < i1);
    }
    const int cnt = ncand < NS ? ncand : NS;
    if (i0 != 0x7fffffff && r0 < NS) sfin4[w][r0] = rec0;
    if (i1 != 0x7fffffff && r1 < NS) sfin4[w][r1] = rec1;
    if (ncand == 0 && lane == 0)     // CUDA semantics: no neighbor -> point 0
        sfin4[w][0] = (f32x4){ps[0], ps[1], ps[2], __int_as_float(0)};
    // fill slots >= cnt with the first (lowest-index) record
    if (lane < NS && lane >= cnt) sfin4[w][lane] = sfin4[w][0];

    // ---- phase 2a: build rows in LDS (cand region now dead) ----
    // row layout: [0]=pad, [1..3]=local_xyz, [4..67]=feature  (stride 68)
    if (lane < NS) {
        const f32x4 v = sfin4[w][lane];
        f32x4 head = {0.f, v.x - qx, v.y - qy, v.z - qz};
        *(f32x4*)(srw + lane * ROWW) = head;             // aligned b128
    }
    const float* __restrict__ fb = feature + (size_t)b * N_ * C_;
#pragma unroll
    for (int h = 0; h < 8; ++h) {
        const int item = h * 64 + lane;                  // 0..511 = 32 samples x 16 chunks
        const int sv = item >> 4;                        // sample
        const int kv = item & 15;                        // 16B chunk
        const int iv = __float_as_int(sfin4[w][sv].w);
        const f32x4 d = *(const f32x4*)(fb + (size_t)iv * C_ + kv * 4);  // coalesced
        *(f32x4*)(srw + sv * ROWW + 4 + kv * 4) = d;     // aligned b128
    }

    // ---- phase 2b: aligned f32x4 nt-stores from LDS ----
    f32x4* __restrict__ outq4 = (f32x4*)(out + (size_t)q * PERQ);
    for (int o4 = lane; o4 < PERQ4; o4 += 64) {
        const int o   = o4 * 4;
        const int s0  = (o * 1957) >> 17;                // exact /67 on [0,2144)
        const int thr = 67 * s0 + 67 - o;                // e >= thr -> next sample
        f32x4 v;
#pragma unroll
        for (int e = 0; e < 4; ++e) {
            const int inc = (e >= thr) ? 1 : 0;          // skip row pad on crossing
            v[e] = srw[o + e + s0 + 1 + inc];
        }
        __builtin_nontemporal_store(v, outq4 + o4);      // full-line tiling
    }
}

// ---- fallback (proven R3 kernel) if ws too small ----
#define NWF 8
#define TILEF 1024
#define NTILEF (N_ / TILEF)

__global__ __launch_bounds__(NWF * 64) void ballquery_fallback(
    const float* __restrict__ new_xyz, const float* __restrict__ pointset,
    const float* __restrict__ feature, float* __restrict__ out)
{
    const int tid  = threadIdx.x;
    const int w    = tid >> 6;
    const int lane = tid & 63;
    const int q    = blockIdx.x * NWF + w;
    const int b    = q >> 11;

    __shared__ float4 spts[TILEF];
    __shared__ int    sidx[NWF][NS];
    __shared__ int    s_done;

    const float qx = new_xyz[q*3+0], qy = new_xyz[q*3+1], qz = new_xyz[q*3+2];
    const float* __restrict__ ps = pointset + (size_t)b * N_ * 3;

    if (tid == 0) s_done = 0;
    int cnt = 0; bool counted = false;

    for (int t = 0; t < NTILEF; ++t) {
        __syncthreads();
        if (s_done == NWF) break;
        {
            const float* __restrict__ tp = ps + t * TILEF * 3;
            float* __restrict__ sp = (float*)spts;
            for (int d = tid; d < TILEF * 3; d += NWF * 64) {
                const int p = d / 3;
                sp[p * 4 + (d - p * 3)] = tp[d];
            }
        }
        __syncthreads();
        if (cnt < NS) {
#pragma unroll 4
            for (int it = 0; it < TILEF / 64; ++it) {
                const float4 p = spts[it * 64 + lane];
                const float dx = qx - p.x, dy = qy - p.y, dz = qz - p.z;
                const float d2 = __fadd_rn(__fadd_rn(__fmul_rn(dx,dx), __fmul_rn(dy,dy)),
                                           __fmul_rn(dz,dz));
                const bool in = d2 < RADIUS2;
                const unsigned long long mk = __ballot(in);
                const unsigned pre = __builtin_amdgcn_mbcnt_hi(
                    (unsigned)(mk >> 32), __builtin_amdgcn_mbcnt_lo((unsigned)mk, 0u));
                if (in) {
                    const int slot = cnt + (int)pre;
                    if (slot < NS) sidx[w][slot] = t * TILEF + it * 64 + lane;
                }
                cnt += (int)__popcll(mk);
            }
        }
        if (!counted && cnt >= NS) { counted = true; if (lane == 0) atomicAdd(&s_done, 1); }
    }
    if (cnt > NS) cnt = NS;
    const int first = (cnt > 0) ? sidx[w][0] : 0;
    if (lane < NS && lane >= cnt) sidx[w][lane] = first;

    const float* __restrict__ fb = feature + (size_t)b * N_ * C_;
    float* __restrict__ outq = out + (size_t)q * PERQ;
    int s = 0, c = lane;
    for (int o = lane; o < PERQ; o += 64) {
        const int i = sidx[w][s];
        float v;
        if (c < 3) v = ps[i*3+c] - new_xyz[q*3+c];
        else       v = fb[(size_t)i * C_ + (c - 3)];
        outq[o] = v;
        c += 64;
        if (c >= OUTW) { c -= OUTW; s += 1; }
    }
}

extern "C" void kernel_launch(void* const* d_in, const int* in_sizes, int n_in,
                              void* d_out, int out_size, void* d_ws, size_t ws_size,
                              hipStream_t stream) {
    const float* new_xyz  = (const float*)d_in[0];
    const float* pointset = (const float*)d_in[1];
    const float* feature  = (const float*)d_in[2];
    float* out = (float*)d_out;

    const size_t cs_bytes = (size_t)B_ * (NC + 1) * sizeof(int);   // 16016 (16B aligned)
    const size_t needed   = cs_bytes + (size_t)B_ * N_ * sizeof(float4);
    if (ws_size >= needed) {
        int*    cellstart = (int*)d_ws;
        float4* sorted4   = (float4*)((char*)d_ws + cs_bytes);
        build_grid<<<B_, 1024, 0, stream>>>(pointset, cellstart, sorted4);
        query_group<<<(B_ * M_) / 4, 256, 0, stream>>>(
            new_xyz, pointset, feature, cellstart, sorted4, out);
    } else {
        ballquery_fallback<<<(B_ * M_) / NWF, NWF * 64, 0, stream>>>(
            new_xyz, pointset, feature, out);
    }
}